// Round 3
// baseline (523.938 us; speedup 1.0000x reference)
//
#include <hip/hip_runtime.h>
#include <hip/hip_bf16.h>

typedef unsigned short u16;
typedef __attribute__((ext_vector_type(8))) _Float16 half8;
typedef __attribute__((ext_vector_type(4))) float f32x4;

#define BKP 40  // LDS row stride (halfwords): 16B-aligned rows, 2-way-max bank aliasing

__device__ __forceinline__ u16 f2h(float f) {
  _Float16 h = (_Float16)f;  // RNE v_cvt_f16_f32
  union { _Float16 h; u16 u; } a; a.h = h;
  return a.u;
}

__device__ __forceinline__ float silu_f(float y) {
  return y / (1.0f + __expf(-y));
}

enum { EPI_BNSILU_N = 0, EPI_BIAS_N, EPI_BIAS_M, EPI_RAW_F32, EPI_RAW_F16, EPI_BNSILU_RES_M };

// C[m,n] = sum_k A[m,k]*B[n,k]  (both operands row-major, K-contiguous = "NT" GEMM)
// 128x128 tile, BK=32, 4 waves, 64x64 per wave via 4x4 of 16x16x32 fp16 MFMA.
template<int EPI>
__global__ __launch_bounds__(256, 2)
void gemm_nt(const u16* __restrict__ A, long long a_bs, int lda,
             const u16* __restrict__ B, long long b_bs, int ldb,
             void* __restrict__ Cout, long long c_bs, int ldc,
             int K,
             const float* __restrict__ p0, const float* __restrict__ p1,
             const float* __restrict__ res, long long res_bs)
{
  __shared__ u16 lA[128 * BKP];
  __shared__ u16 lB[128 * BKP];
  const int bz = blockIdx.z;
  const u16* Ab = A + (long long)bz * a_bs;
  const u16* Bb = B + (long long)bz * b_bs;
  const int m0 = blockIdx.x * 128;
  const int n0 = blockIdx.y * 128;
  const int t = threadIdx.x;
  const int lane = t & 63;
  const int wv = t >> 6;
  const int wm = (wv & 1) * 64;
  const int wn = (wv >> 1) * 64;
  const int q = lane >> 4;       // quad
  const int lr = lane & 15;

  f32x4 acc[4][4];
#pragma unroll
  for (int i = 0; i < 4; ++i)
#pragma unroll
    for (int j = 0; j < 4; ++j)
      acc[i][j] = (f32x4){0.f, 0.f, 0.f, 0.f};

  // staging: 512 chunks of 8 fp16 per operand; thread t does chunks t and t+256
  const int r0 = t >> 2;
  const int kc = (t & 3) * 8;
  const int r1 = r0 + 64;

  for (int k0 = 0; k0 < K; k0 += 32) {
    __syncthreads();
    *(half8*)&lA[r0 * BKP + kc] = *(const half8*)(Ab + (long long)(m0 + r0) * lda + k0 + kc);
    *(half8*)&lA[r1 * BKP + kc] = *(const half8*)(Ab + (long long)(m0 + r1) * lda + k0 + kc);
    *(half8*)&lB[r0 * BKP + kc] = *(const half8*)(Bb + (long long)(n0 + r0) * ldb + k0 + kc);
    *(half8*)&lB[r1 * BKP + kc] = *(const half8*)(Bb + (long long)(n0 + r1) * ldb + k0 + kc);
    __syncthreads();
    half8 af[4], bfr[4];
#pragma unroll
    for (int i = 0; i < 4; ++i)
      af[i] = *(const half8*)&lA[(wm + i * 16 + lr) * BKP + q * 8];
#pragma unroll
    for (int j = 0; j < 4; ++j)
      bfr[j] = *(const half8*)&lB[(wn + j * 16 + lr) * BKP + q * 8];
#pragma unroll
    for (int i = 0; i < 4; ++i)
#pragma unroll
      for (int j = 0; j < 4; ++j)
        acc[i][j] = __builtin_amdgcn_mfma_f32_16x16x32_f16(af[i], bfr[j], acc[i][j], 0, 0, 0);
  }

  // epilogue: C/D layout col=lane&15, row=quad*4+reg
#pragma unroll
  for (int i = 0; i < 4; ++i) {
#pragma unroll
    for (int j = 0; j < 4; ++j) {
#pragma unroll
      for (int r = 0; r < 4; ++r) {
        const int m = m0 + wm + i * 16 + q * 4 + r;
        const int n = n0 + wn + j * 16 + lr;
        float v = acc[i][j][r];
        if constexpr (EPI == EPI_BNSILU_N) {
          v = silu_f(v * (p0[n] * 0.99999500003749969f) + p1[n]);
          ((u16*)Cout)[(long long)bz * c_bs + (long long)m * ldc + n] = f2h(v);
        } else if constexpr (EPI == EPI_BIAS_N) {
          v += p0[n];
          ((u16*)Cout)[(long long)bz * c_bs + (long long)m * ldc + n] = f2h(v);
        } else if constexpr (EPI == EPI_BIAS_M) {
          v += p0[m];
          ((u16*)Cout)[(long long)bz * c_bs + (long long)m * ldc + n] = f2h(v);
        } else if constexpr (EPI == EPI_RAW_F32) {
          ((float*)Cout)[(long long)bz * c_bs + (long long)m * ldc + n] = v;
        } else if constexpr (EPI == EPI_RAW_F16) {
          ((u16*)Cout)[(long long)bz * c_bs + (long long)m * ldc + n] = f2h(v);
        } else {  // EPI_BNSILU_RES_M
          v = silu_f(v * (p0[m] * 0.99999500003749969f) + p1[m]);
          v += res[(long long)bz * res_bs + (long long)m * ldc + n];
          ((float*)Cout)[(long long)bz * c_bs + (long long)m * ldc + n] = v;
        }
      }
    }
  }
}

// x [B,512,1024] fp32 -> xT [B,1024,512] fp16 (token-major)
__global__ __launch_bounds__(256)
void transpose_x(const float* __restrict__ x, u16* __restrict__ xT) {
  __shared__ float tile[32][33];
  const int b = blockIdx.z;
  const int n0 = blockIdx.x * 32;
  const int d0 = blockIdx.y * 32;
  const int tx = threadIdx.x;  // 0..31
  const int ty = threadIdx.y;  // 0..7
  const float* src = x + (long long)b * 524288;
#pragma unroll
  for (int i = 0; i < 4; ++i)
    tile[ty + 8 * i][tx] = src[(long long)(d0 + ty + 8 * i) * 1024 + n0 + tx];
  __syncthreads();
  u16* dst = xT + (long long)b * 524288;
#pragma unroll
  for (int i = 0; i < 4; ++i)
    dst[(long long)(n0 + ty + 8 * i) * 512 + d0 + tx] = f2h(tile[tx][ty + 8 * i]);
}

// fp32->fp16 for all 6 weight matrices, packed: w1|wq|wk|wv|we|w2
__global__ __launch_bounds__(256)
void convert_w(const float* __restrict__ w1, const float* __restrict__ wq,
               const float* __restrict__ wk, const float* __restrict__ wv,
               const float* __restrict__ we, const float* __restrict__ w2,
               u16* __restrict__ dst) {
  int id = blockIdx.x * 256 + threadIdx.x;  // 524288 total
  int off = id;
  float v;
  if (off < 131072) v = w1[off];
  else if ((off -= 131072) < 65536) v = wq[off];
  else if ((off -= 65536) < 65536) v = wk[off];
  else if ((off -= 65536) < 65536) v = wv[off];
  else if ((off -= 65536) < 65536) v = we[off];
  else { off -= 65536; v = w2[off]; }
  dst[id] = f2h(v);
}

// qcat[b, n, 256+c] = fp16(rel_h[c, n>>5] + rel_w[c, n&31])
__global__ __launch_bounds__(256)
void fill_pos(const float* __restrict__ rh, const float* __restrict__ rw,
              u16* __restrict__ qcat) {
  long long id = (long long)blockIdx.x * 256 + threadIdx.x;  // B*N*C = 8388608
  int c = (int)(id & 255);
  int n = (int)((id >> 8) & 1023);
  int b = (int)(id >> 18);
  float v = rh[c * 32 + (n >> 5)] + rw[c * 32 + (n & 31)];
  qcat[(long long)b * 524288 + (long long)n * 512 + 256 + c] = f2h(v);
}

// in-place softmax: fp32 row of 1024 -> fp16 row of 1024 written over its own start
__global__ __launch_bounds__(256)
void softmax_rows(float* __restrict__ logits) {
  __shared__ float red[8];
  const long long row = blockIdx.x;  // chunk-local row
  float* p = logits + row * 1024;
  const int t = threadIdx.x;
  float4 v = ((const float4*)p)[t];
  float mx = fmaxf(fmaxf(v.x, v.y), fmaxf(v.z, v.w));
#pragma unroll
  for (int off = 32; off > 0; off >>= 1) mx = fmaxf(mx, __shfl_down(mx, off));
  const int lane = t & 63, w = t >> 6;
  if (lane == 0) red[w] = mx;
  __syncthreads();
  mx = fmaxf(fmaxf(red[0], red[1]), fmaxf(red[2], red[3]));
  float e0 = __expf(v.x - mx), e1 = __expf(v.y - mx),
        e2 = __expf(v.z - mx), e3 = __expf(v.w - mx);
  float s = e0 + e1 + e2 + e3;
#pragma unroll
  for (int off = 32; off > 0; off >>= 1) s += __shfl_down(s, off);
  if (lane == 0) red[4 + w] = s;
  __syncthreads();
  const float inv = 1.0f / (red[4] + red[5] + red[6] + red[7]);
  u16* o = (u16*)p;
  o[4 * t + 0] = f2h(e0 * inv);
  o[4 * t + 1] = f2h(e1 * inv);
  o[4 * t + 2] = f2h(e2 * inv);
  o[4 * t + 3] = f2h(e3 * inv);
}

extern "C" void kernel_launch(void* const* d_in, const int* in_sizes, int n_in,
                              void* d_out, int out_size, void* d_ws, size_t ws_size,
                              hipStream_t stream) {
  const float* x  = (const float*)d_in[0];
  const float* w1 = (const float*)d_in[1];
  const float* g1 = (const float*)d_in[2];
  const float* b1 = (const float*)d_in[3];
  const float* wq = (const float*)d_in[4];
  const float* bq = (const float*)d_in[5];
  const float* wk = (const float*)d_in[6];
  const float* bk = (const float*)d_in[7];
  const float* wv = (const float*)d_in[8];
  const float* bv = (const float*)d_in[9];
  const float* we = (const float*)d_in[10];
  const float* be = (const float*)d_in[11];
  const float* rh = (const float*)d_in[12];
  const float* rw = (const float*)d_in[13];
  const float* w2 = (const float*)d_in[14];
  const float* g2 = (const float*)d_in[15];
  const float* b2 = (const float*)d_in[16];
  float* out = (float*)d_out;
  char* ws = (char*)d_ws;

  // ---- workspace layout (total 135,266,304 B ~= 129 MiB) with lifetime overlays ----
  // [0, 33554432)        xT  [B,1024,512] f16    (dead after cv1)
  //                      logits chunk [8,1024,1024] f32 (attention phase, reused 4x)
  // [33554432, 50331648) x1t [B,1024,256] f16    (dead after v GEMM)
  //                      outt [B,1024,256] f16   (written by PV, read by cv2)
  // [50331648, 83886080) qcat [B,1024,512] f16   (q | pos)
  // [83886080,117440512) kcat [B,1024,512] f16   (k | e)
  // [117440512,134217728) vbuf [B,256,1024] f16
  // [134217728,135266304) wbuf packed f16 weights
  u16* xT       = (u16*)(ws + 0);
  float* logits = (float*)(ws + 0);
  u16* x1t      = (u16*)(ws + 33554432);
  u16* outt     = (u16*)(ws + 33554432);
  u16* qcat     = (u16*)(ws + 50331648);
  u16* kcat     = (u16*)(ws + 83886080);
  u16* vbuf     = (u16*)(ws + 117440512);
  u16* wbuf     = (u16*)(ws + 134217728);

  u16* w1b = wbuf;
  u16* wqb = wbuf + 131072;
  u16* wkb = wqb + 65536;
  u16* wvb = wkb + 65536;
  u16* web = wvb + 65536;
  u16* w2b = web + 65536;

  transpose_x<<<dim3(32, 16, 32), dim3(32, 8), 0, stream>>>(x, xT);
  convert_w<<<dim3(2048), 256, 0, stream>>>(w1, wq, wk, wv, we, w2, wbuf);
  fill_pos<<<dim3(32768), 256, 0, stream>>>(rh, rw, qcat);

  // cv1: x1t[n,c] = silu(bn(xT[n,:] . w1[c,:]))   M=1024 N=256 K=512
  gemm_nt<EPI_BNSILU_N><<<dim3(8, 2, 32), 256, 0, stream>>>(
      xT, 524288LL, 512, w1b, 0LL, 512, x1t, 262144LL, 256, 512, g1, b1, nullptr, 0LL);
  // q -> qcat[:, :256]   M=1024 N=256 K=256
  gemm_nt<EPI_BIAS_N><<<dim3(8, 2, 32), 256, 0, stream>>>(
      x1t, 262144LL, 256, wqb, 0LL, 256, qcat, 524288LL, 512, 256, bq, nullptr, nullptr, 0LL);
  // k -> kcat[:, :256]
  gemm_nt<EPI_BIAS_N><<<dim3(8, 2, 32), 256, 0, stream>>>(
      x1t, 262144LL, 256, wkb, 0LL, 256, kcat, 524288LL, 512, 256, bk, nullptr, nullptr, 0LL);
  // e -> kcat[:, 256:]
  gemm_nt<EPI_BIAS_N><<<dim3(8, 2, 32), 256, 0, stream>>>(
      x1t, 262144LL, 256, web, 0LL, 256, kcat + 256, 524288LL, 512, 256, be, nullptr, nullptr, 0LL);
  // v[c,j]: A=wv [256,256], B=x1t   M=256 N=1024 K=256
  gemm_nt<EPI_BIAS_M><<<dim3(2, 8, 32), 256, 0, stream>>>(
      wvb, 0LL, 256, x1t, 262144LL, 256, vbuf, 262144LL, 1024, 256, bv, nullptr, nullptr, 0LL);

  // attention in 4 chunks of 8 batches (logits buffer reused; overlays dead xT)
  for (int cb = 0; cb < 32; cb += 8) {
    // logits[i,j] = qcat[i,:] . kcat[j,:]   M=1024 N=1024 K=512, f32 out
    gemm_nt<EPI_RAW_F32><<<dim3(8, 8, 8), 256, 0, stream>>>(
        qcat + (long long)cb * 524288, 524288LL, 512,
        kcat + (long long)cb * 524288, 524288LL, 512,
        logits, 1048576LL, 1024, 512, nullptr, nullptr, nullptr, 0LL);
    // softmax in place (fp16 rows at u16-stride 2048)
    softmax_rows<<<dim3(8192), 256, 0, stream>>>(logits);
    // outt[i,c] = attn[i,:] . v[c,:]   M=1024 N=256 K=1024
    gemm_nt<EPI_RAW_F16><<<dim3(8, 2, 8), 256, 0, stream>>>(
        (const u16*)logits, 2097152LL, 2048,
        vbuf + (long long)cb * 262144, 262144LL, 1024,
        outt + (long long)cb * 262144, 262144LL, 256, 1024,
        nullptr, nullptr, nullptr, 0LL);
  }

  // cv2 + residual: out[b,d,n] = x[b,d,n] + silu(bn(w2[d,:] . outt[n,:]))   M=512 N=1024 K=256
  gemm_nt<EPI_BNSILU_RES_M><<<dim3(4, 8, 32), 256, 0, stream>>>(
      w2b, 0LL, 256, outt, 262144LL, 256, out, 524288LL, 1024, 256, g2, b2, x, 524288LL);
}

// Round 4
// 397.171 us; speedup vs baseline: 1.3192x; 1.3192x over previous
//
#include <hip/hip_runtime.h>
#include <hip/hip_bf16.h>

typedef unsigned short u16;
typedef __attribute__((ext_vector_type(8))) _Float16 half8;
typedef __attribute__((ext_vector_type(8))) short short8;
typedef __attribute__((ext_vector_type(4))) float f32x4;

#define BKP 40  // LDS row stride (halfwords): 16B-aligned rows, 2-way-max bank aliasing

__device__ __forceinline__ u16 f2h(float f) {
  _Float16 h = (_Float16)f;  // RNE v_cvt_f16_f32
  union { _Float16 h; u16 u; } a; a.h = h;
  return a.u;
}

__device__ __forceinline__ float h2f(u16 u) {
  union { _Float16 h; u16 u; } a; a.u = u;
  return (float)a.h;
}

__device__ __forceinline__ float silu_f(float y) {
  return y / (1.0f + __expf(-y));
}

enum { EPI_BNSILU_N = 0, EPI_BIAS_N, EPI_BIAS_M, EPI_RAW_F32, EPI_RAW_F16, EPI_BNSILU_RES_M };

// C[m,n] = sum_k A[m,k]*B[n,k]  (both operands row-major, K-contiguous = "NT" GEMM)
// 128x128 tile, BK=32, 4 waves, 64x64 per wave via 4x4 of 16x16x32 fp16 MFMA.
template<int EPI>
__global__ __launch_bounds__(256, 2)
void gemm_nt(const u16* __restrict__ A, long long a_bs, int lda,
             const u16* __restrict__ B, long long b_bs, int ldb,
             void* __restrict__ Cout, long long c_bs, int ldc,
             int K,
             const float* __restrict__ p0, const float* __restrict__ p1,
             const float* __restrict__ res, long long res_bs)
{
  __shared__ u16 lA[128 * BKP];
  __shared__ u16 lB[128 * BKP];
  const int bz = blockIdx.z;
  const u16* Ab = A + (long long)bz * a_bs;
  const u16* Bb = B + (long long)bz * b_bs;
  const int m0 = blockIdx.x * 128;
  const int n0 = blockIdx.y * 128;
  const int t = threadIdx.x;
  const int lane = t & 63;
  const int wv = t >> 6;
  const int wm = (wv & 1) * 64;
  const int wn = (wv >> 1) * 64;
  const int q = lane >> 4;       // quad
  const int lr = lane & 15;

  f32x4 acc[4][4];
#pragma unroll
  for (int i = 0; i < 4; ++i)
#pragma unroll
    for (int j = 0; j < 4; ++j)
      acc[i][j] = (f32x4){0.f, 0.f, 0.f, 0.f};

  // staging: 512 chunks of 8 fp16 per operand; thread t does chunks t and t+256
  const int r0 = t >> 2;
  const int kc = (t & 3) * 8;
  const int r1 = r0 + 64;

  for (int k0 = 0; k0 < K; k0 += 32) {
    __syncthreads();
    *(half8*)&lA[r0 * BKP + kc] = *(const half8*)(Ab + (long long)(m0 + r0) * lda + k0 + kc);
    *(half8*)&lA[r1 * BKP + kc] = *(const half8*)(Ab + (long long)(m0 + r1) * lda + k0 + kc);
    *(half8*)&lB[r0 * BKP + kc] = *(const half8*)(Bb + (long long)(n0 + r0) * ldb + k0 + kc);
    *(half8*)&lB[r1 * BKP + kc] = *(const half8*)(Bb + (long long)(n0 + r1) * ldb + k0 + kc);
    __syncthreads();
    half8 af[4], bfr[4];
#pragma unroll
    for (int i = 0; i < 4; ++i)
      af[i] = *(const half8*)&lA[(wm + i * 16 + lr) * BKP + q * 8];
#pragma unroll
    for (int j = 0; j < 4; ++j)
      bfr[j] = *(const half8*)&lB[(wn + j * 16 + lr) * BKP + q * 8];
#pragma unroll
    for (int i = 0; i < 4; ++i)
#pragma unroll
      for (int j = 0; j < 4; ++j)
        acc[i][j] = __builtin_amdgcn_mfma_f32_16x16x32_f16(af[i], bfr[j], acc[i][j], 0, 0, 0);
  }

  // epilogue: C/D layout col=lane&15, row=quad*4+reg
#pragma unroll
  for (int i = 0; i < 4; ++i) {
#pragma unroll
    for (int j = 0; j < 4; ++j) {
#pragma unroll
      for (int r = 0; r < 4; ++r) {
        const int m = m0 + wm + i * 16 + q * 4 + r;
        const int n = n0 + wn + j * 16 + lr;
        float v = acc[i][j][r];
        if constexpr (EPI == EPI_BNSILU_N) {
          v = silu_f(v * (p0[n] * 0.99999500003749969f) + p1[n]);
          ((u16*)Cout)[(long long)bz * c_bs + (long long)m * ldc + n] = f2h(v);
        } else if constexpr (EPI == EPI_BIAS_N) {
          v += p0[n];
          ((u16*)Cout)[(long long)bz * c_bs + (long long)m * ldc + n] = f2h(v);
        } else if constexpr (EPI == EPI_BIAS_M) {
          v += p0[m];
          ((u16*)Cout)[(long long)bz * c_bs + (long long)m * ldc + n] = f2h(v);
        } else if constexpr (EPI == EPI_RAW_F32) {
          ((float*)Cout)[(long long)bz * c_bs + (long long)m * ldc + n] = v;
        } else if constexpr (EPI == EPI_RAW_F16) {
          ((u16*)Cout)[(long long)bz * c_bs + (long long)m * ldc + n] = f2h(v);
        } else {  // EPI_BNSILU_RES_M
          v = silu_f(v * (p0[m] * 0.99999500003749969f) + p1[m]);
          v += res[(long long)bz * res_bs + (long long)m * ldc + n];
          ((float*)Cout)[(long long)bz * c_bs + (long long)m * ldc + n] = v;
        }
      }
    }
  }
}

// x [B,512,1024] fp32 -> xT [B,1024,512] fp16 (token-major); paired u32 stores
__global__ __launch_bounds__(256)
void transpose_x(const float* __restrict__ x, u16* __restrict__ xT) {
  __shared__ float tile[64][33];
  const int b = blockIdx.z;
  const int n0 = blockIdx.x * 32;
  const int d0 = blockIdx.y * 64;
  const int tx = threadIdx.x;  // 0..31
  const int ty = threadIdx.y;  // 0..7
  const float* src = x + (long long)b * 524288;
#pragma unroll
  for (int i = 0; i < 8; ++i)
    tile[ty + 8 * i][tx] = src[(long long)(d0 + ty + 8 * i) * 1024 + n0 + tx];
  __syncthreads();
  u16* dst = xT + (long long)b * 524288;
#pragma unroll
  for (int i = 0; i < 4; ++i) {
    const int n = ty + 8 * i;
    unsigned lo = (unsigned)f2h(tile[2 * tx][n]);
    unsigned hi = (unsigned)f2h(tile[2 * tx + 1][n]);
    *(unsigned*)&dst[(long long)(n0 + n) * 512 + d0 + 2 * tx] = lo | (hi << 16);
  }
}

// fp32->fp16 for all 6 weight matrices, packed: w1|wq|wk|wv|we|w2
__global__ __launch_bounds__(256)
void convert_w(const float* __restrict__ w1, const float* __restrict__ wq,
               const float* __restrict__ wk, const float* __restrict__ wv,
               const float* __restrict__ we, const float* __restrict__ w2,
               u16* __restrict__ dst) {
  int id = blockIdx.x * 256 + threadIdx.x;  // 524288 total
  int off = id;
  float v;
  if (off < 131072) v = w1[off];
  else if ((off -= 131072) < 65536) v = wq[off];
  else if ((off -= 65536) < 65536) v = wk[off];
  else if ((off -= 65536) < 65536) v = wv[off];
  else if ((off -= 65536) < 65536) v = we[off];
  else { off -= 65536; v = w2[off]; }
  dst[id] = f2h(v);
}

// posb[n,c] = fp16(rel_h[c, n>>5] + rel_w[c, n&31])  — computed ONCE (batch-independent)
__global__ __launch_bounds__(256)
void pos_compute(const float* __restrict__ rh, const float* __restrict__ rw,
                 u16* __restrict__ posb) {
  const int n = blockIdx.x;   // 0..1023
  const int c = threadIdx.x;  // 0..255
  posb[n * 256 + c] = f2h(rh[c * 32 + (n >> 5)] + rw[c * 32 + (n & 31)]);
}

// broadcast posb into qcat[b, n, 256:512] for all 32 batches, 16B stores
__global__ __launch_bounds__(256)
void pos_bcast(const u16* __restrict__ posb, u16* __restrict__ qcat) {
  const int id = blockIdx.x * 256 + threadIdx.x;  // 1,048,576 total
  const int c8 = id & 31;
  const int n = (id >> 5) & 1023;
  const int b = id >> 15;
  *(short8*)&qcat[(long long)b * 524288 + (long long)n * 512 + 256 + c8 * 8] =
      *(const short8*)&posb[n * 256 + c8 * 8];
}

// in-place softmax on fp16 rows of 1024
__global__ __launch_bounds__(256)
void softmax_rows(u16* __restrict__ logits) {
  __shared__ float red[8];
  u16* p = logits + (long long)blockIdx.x * 1024;
  const int t = threadIdx.x;
  ushort4 raw = ((const ushort4*)p)[t];
  float v0 = h2f(raw.x), v1 = h2f(raw.y), v2 = h2f(raw.z), v3 = h2f(raw.w);
  float mx = fmaxf(fmaxf(v0, v1), fmaxf(v2, v3));
#pragma unroll
  for (int off = 32; off > 0; off >>= 1) mx = fmaxf(mx, __shfl_down(mx, off));
  const int lane = t & 63, w = t >> 6;
  if (lane == 0) red[w] = mx;
  __syncthreads();
  mx = fmaxf(fmaxf(red[0], red[1]), fmaxf(red[2], red[3]));
  float e0 = __expf(v0 - mx), e1 = __expf(v1 - mx),
        e2 = __expf(v2 - mx), e3 = __expf(v3 - mx);
  float s = e0 + e1 + e2 + e3;
#pragma unroll
  for (int off = 32; off > 0; off >>= 1) s += __shfl_down(s, off);
  if (lane == 0) red[4 + w] = s;
  __syncthreads();
  const float inv = 1.0f / (red[4] + red[5] + red[6] + red[7]);
  ushort4 o;
  o.x = f2h(e0 * inv); o.y = f2h(e1 * inv); o.z = f2h(e2 * inv); o.w = f2h(e3 * inv);
  ((ushort4*)p)[t] = o;
}

extern "C" void kernel_launch(void* const* d_in, const int* in_sizes, int n_in,
                              void* d_out, int out_size, void* d_ws, size_t ws_size,
                              hipStream_t stream) {
  const float* x  = (const float*)d_in[0];
  const float* w1 = (const float*)d_in[1];
  const float* g1 = (const float*)d_in[2];
  const float* b1 = (const float*)d_in[3];
  const float* wq = (const float*)d_in[4];
  const float* bq = (const float*)d_in[5];
  const float* wk = (const float*)d_in[6];
  const float* bk = (const float*)d_in[7];
  const float* wv = (const float*)d_in[8];
  const float* bv = (const float*)d_in[9];
  const float* we = (const float*)d_in[10];
  const float* be = (const float*)d_in[11];
  const float* rh = (const float*)d_in[12];
  const float* rw = (const float*)d_in[13];
  const float* w2 = (const float*)d_in[14];
  const float* g2 = (const float*)d_in[15];
  const float* b2 = (const float*)d_in[16];
  float* out = (float*)d_out;
  char* ws = (char*)d_ws;

  // ---- workspace layout (total 135,266,304 B — identical to proven round-2 size) ----
  // [0, 33554432)         xT [B,1024,512] f16 (dead after cv1)
  //                       logits chunk [16,1024,1024] f16 (attention phase, reused 2x)
  // [33554432, 50331648)  x1t [B,1024,256] f16 (dead after v GEMM)
  //                       outt [B,1024,256] f16 (written by PV, read by cv2)
  // [50331648, 83886080)  qcat [B,1024,512] f16  (q | pos)
  // [83886080,117440512)  kcat [B,1024,512] f16  (k | e)
  // [117440512,134217728) vbuf [B,256,1024] f16; posb (512 KB) overlays its head
  //                       (posb dead before the v GEMM writes vbuf)
  // [134217728,135266304) wbuf packed f16 weights
  u16* xT      = (u16*)(ws + 0);
  u16* logitsH = (u16*)(ws + 0);
  u16* x1t     = (u16*)(ws + 33554432);
  u16* outt    = (u16*)(ws + 33554432);
  u16* qcat    = (u16*)(ws + 50331648);
  u16* kcat    = (u16*)(ws + 83886080);
  u16* vbuf    = (u16*)(ws + 117440512);
  u16* posb    = (u16*)(ws + 117440512);
  u16* wbuf    = (u16*)(ws + 134217728);

  u16* w1b = wbuf;
  u16* wqb = wbuf + 131072;
  u16* wkb = wqb + 65536;
  u16* wvb = wkb + 65536;
  u16* web = wvb + 65536;
  u16* w2b = web + 65536;

  transpose_x<<<dim3(32, 8, 32), dim3(32, 8), 0, stream>>>(x, xT);
  convert_w<<<dim3(2048), 256, 0, stream>>>(w1, wq, wk, wv, we, w2, wbuf);
  pos_compute<<<dim3(1024), 256, 0, stream>>>(rh, rw, posb);
  pos_bcast<<<dim3(4096), 256, 0, stream>>>(posb, qcat);

  // cv1: x1t[n,c] = silu(bn(xT[n,:] . w1[c,:]))   M=1024 N=256 K=512
  gemm_nt<EPI_BNSILU_N><<<dim3(8, 2, 32), 256, 0, stream>>>(
      xT, 524288LL, 512, w1b, 0LL, 512, x1t, 262144LL, 256, 512, g1, b1, nullptr, 0LL);
  // q -> qcat[:, :256]   M=1024 N=256 K=256
  gemm_nt<EPI_BIAS_N><<<dim3(8, 2, 32), 256, 0, stream>>>(
      x1t, 262144LL, 256, wqb, 0LL, 256, qcat, 524288LL, 512, 256, bq, nullptr, nullptr, 0LL);
  // k -> kcat[:, :256]
  gemm_nt<EPI_BIAS_N><<<dim3(8, 2, 32), 256, 0, stream>>>(
      x1t, 262144LL, 256, wkb, 0LL, 256, kcat, 524288LL, 512, 256, bk, nullptr, nullptr, 0LL);
  // e -> kcat[:, 256:]
  gemm_nt<EPI_BIAS_N><<<dim3(8, 2, 32), 256, 0, stream>>>(
      x1t, 262144LL, 256, web, 0LL, 256, kcat + 256, 524288LL, 512, 256, be, nullptr, nullptr, 0LL);
  // v[c,j]: A=wv [256,256], B=x1t   M=256 N=1024 K=256  (posb dead from here)
  gemm_nt<EPI_BIAS_M><<<dim3(2, 8, 32), 256, 0, stream>>>(
      wvb, 0LL, 256, x1t, 262144LL, 256, vbuf, 262144LL, 1024, 256, bv, nullptr, nullptr, 0LL);

  // attention in 2 chunks of 16 batches; fp16 logits chunk overlays dead xT
  for (int cb = 0; cb < 32; cb += 16) {
    // logits[i,j] = qcat[i,:] . kcat[j,:]   M=1024 N=1024 K=512, fp16 out
    gemm_nt<EPI_RAW_F16><<<dim3(8, 8, 16), 256, 0, stream>>>(
        qcat + (long long)cb * 524288, 524288LL, 512,
        kcat + (long long)cb * 524288, 524288LL, 512,
        logitsH, 1048576LL, 1024, 512, nullptr, nullptr, nullptr, 0LL);
    // softmax in place on fp16 rows
    softmax_rows<<<dim3(16384), 256, 0, stream>>>(logitsH);
    // outt[i,c] = attn[i,:] . v[c,:]   M=1024 N=256 K=1024
    gemm_nt<EPI_RAW_F16><<<dim3(8, 2, 16), 256, 0, stream>>>(
        logitsH, 1048576LL, 1024,
        vbuf + (long long)cb * 262144, 262144LL, 1024,
        outt + (long long)cb * 262144, 262144LL, 256, 1024,
        nullptr, nullptr, nullptr, 0LL);
  }

  // cv2 + residual: out[b,d,n] = x[b,d,n] + silu(bn(w2[d,:] . outt[n,:]))   M=512 N=1024 K=256
  gemm_nt<EPI_BNSILU_RES_M><<<dim3(4, 8, 32), 256, 0, stream>>>(
      w2b, 0LL, 256, outt, 262144LL, 256, out, 524288LL, 1024, 256, g2, b2, x, 524288LL);
}